// Round 11
// baseline (198.864 us; speedup 1.0000x reference)
//
#include <hip/hip_runtime.h>
#include <hip/hip_bf16.h>
#include <math.h>

#define HW 784
#define IW 28
#define NB 64
#define BN_EPS 1e-5f

typedef __attribute__((ext_vector_type(8))) short bf16x8;
typedef __attribute__((ext_vector_type(4))) float f32x4;

static __device__ __forceinline__ ushort f2bf(float f) {
    __hip_bfloat16 h = __float2bfloat16(f);
    return *reinterpret_cast<ushort*>(&h);
}
static __device__ __forceinline__ float bf2f(ushort u) {
    return __uint_as_float(((unsigned)u) << 16);
}

// BN+ReLU on a packed 8-channel bf16 uint4, channels [c0..c0+8)
static __device__ __forceinline__ uint4 bn_pack(uint4 v,
    const float* __restrict__ rs, const float* __restrict__ sh, int c0)
{
    float4 ra = *reinterpret_cast<const float4*>(rs + c0);
    float4 rb = *reinterpret_cast<const float4*>(rs + c0 + 4);
    float4 sa = *reinterpret_cast<const float4*>(sh + c0);
    float4 sb = *reinterpret_cast<const float4*>(sh + c0 + 4);
    ushort* u = (ushort*)&v;
    u[0] = f2bf(fmaxf(fmaf(bf2f(u[0]), ra.x, sa.x), 0.f));
    u[1] = f2bf(fmaxf(fmaf(bf2f(u[1]), ra.y, sa.y), 0.f));
    u[2] = f2bf(fmaxf(fmaf(bf2f(u[2]), ra.z, sa.z), 0.f));
    u[3] = f2bf(fmaxf(fmaf(bf2f(u[3]), ra.w, sa.w), 0.f));
    u[4] = f2bf(fmaxf(fmaf(bf2f(u[4]), rb.x, sb.x), 0.f));
    u[5] = f2bf(fmaxf(fmaf(bf2f(u[5]), rb.y, sb.y), 0.f));
    u[6] = f2bf(fmaxf(fmaf(bf2f(u[6]), rb.z, sb.z), 0.f));
    u[7] = f2bf(fmaxf(fmaf(bf2f(u[7]), rb.w, sb.w), 0.f));
    return v;
}

// ---------------------------------------------------------------------------
// prep: ONE kernel, 3 blocks (block t = tensor t). Block-local absmax
// (float4 loads, shfl tree, LDS broadcast — no atomics, no memset) then
// prequant in the same block. Replaces memset+absmax3+prequant3 launches.
// w2 transposed to [co][r*128+ci].
// ---------------------------------------------------------------------------
__global__ __launch_bounds__(1024) void prep_kernel(
    const float* __restrict__ w1, const float* __restrict__ w2,
    const float* __restrict__ w3,
    ushort* __restrict__ o1, ushort* __restrict__ o2,
    ushort* __restrict__ o3)
{
    const int t = blockIdx.x;
    const float* w = t == 0 ? w1 : (t == 1 ? w2 : w3);
    ushort* o = t == 0 ? o1 : (t == 1 ? o2 : o3);
    const int n = (t == 1) ? 147456 : 65536;
    const int tid = threadIdx.x;

    float m = 0.f;
    const float4* w4 = (const float4*)w;
    for (int i = tid; i < n / 4; i += 1024) {
        float4 v = w4[i];
        m = fmaxf(fmaxf(fmaxf(fabsf(v.x), fabsf(v.y)),
                        fmaxf(fabsf(v.z), fabsf(v.w))), m);
    }
#pragma unroll
    for (int off = 32; off > 0; off >>= 1)
        m = fmaxf(m, __shfl_down(m, off, 64));
    __shared__ float sm[16];
    int lane = tid & 63, wid = tid >> 6;
    if (lane == 0) sm[wid] = m;
    __syncthreads();
    if (tid == 0) {
        float b = sm[0];
#pragma unroll
        for (int i = 1; i < 16; ++i) b = fmaxf(b, sm[i]);
        sm[0] = b;
    }
    __syncthreads();
    const float am = sm[0];
    const float scale = am * (1.0f / 127.0f);
    const float inv   = 127.0f / am;

    for (int i = tid; i < n; i += 1024) {
        float q = rintf(w[i] * inv) * scale;
        if (t == 1) {
            int co  = i / 1152;
            int rem = i - co * 1152;
            int ci  = rem / 9;
            int r   = rem - ci * 9;
            o[co * 1152 + r * 128 + ci] = f2bf(q);
        } else {
            o[i] = f2bf(q);
        }
    }
}

// ---------------------------------------------------------------------------
// shared epilogue: write transposed bf16 [hw][C] + per-channel partial stats
// ---------------------------------------------------------------------------
__device__ __forceinline__ void epi_t(
    f32x4 (*acc)[7], ushort* __restrict__ yt_img, float* __restrict__ part,
    int C, int pb, int co0, int colane, int lanehi)
{
#pragma unroll
    for (int fi = 0; fi < 2; ++fi) {
#pragma unroll
        for (int j = 0; j < 7; ++j) {
            int hw = j * 16 + colane;
            int co = co0 + fi * 16 + lanehi * 4;
            ushort4 u;
            u.x = f2bf(acc[fi][j][0]); u.y = f2bf(acc[fi][j][1]);
            u.z = f2bf(acc[fi][j][2]); u.w = f2bf(acc[fi][j][3]);
            *reinterpret_cast<ushort4*>(&yt_img[(size_t)hw * C + co]) = u;
        }
        float s[4] = {0, 0, 0, 0}, q[4] = {0, 0, 0, 0};
#pragma unroll
        for (int j = 0; j < 7; ++j)
#pragma unroll
            for (int r = 0; r < 4; ++r) {
                float v = acc[fi][j][r];
                s[r] += v; q[r] += v * v;
            }
#pragma unroll
        for (int m = 1; m < 16; m <<= 1)
#pragma unroll
            for (int r = 0; r < 4; ++r) {
                s[r] += __shfl_xor(s[r], m, 64);
                q[r] += __shfl_xor(q[r], m, 64);
            }
        if (colane == 0) {
#pragma unroll
            for (int r = 0; r < 4; ++r) {
                int co = co0 + fi * 16 + lanehi * 4 + r;
                part[(size_t)co * 448 + pb]       = s[r];
                part[(size_t)(C + co) * 448 + pb] = q[r];
            }
        }
    }
}

// ---------------------------------------------------------------------------
// conv1: 1x1 K=512, fp32 x[n][ci][hw] -> RAW y1t[n][hw][128] bf16 + stats
// ---------------------------------------------------------------------------
__global__ __launch_bounds__(256, 2) void conv1_mfma(
    const float* __restrict__ X, const ushort* __restrict__ Wq,
    ushort* __restrict__ y1t, float* __restrict__ part)
{
    __shared__ ushort lds[2][112 * 40];
    const int n = blockIdx.z, hwt = blockIdx.x;
    const int tid = threadIdx.x, lane = tid & 63, wv = tid >> 6;
    const int colane = lane & 15, lanehi = lane >> 4, klane = lanehi * 8;
    const float* __restrict__ Xn = X + (size_t)n * 512 * HW + hwt * 112;

    int s_hw[4], s_cg[4];
#pragma unroll
    for (int it = 0; it < 4; ++it) {
        int idx = tid + it * 256;
        s_hw[it] = idx % 112; s_cg[it] = idx / 112;
    }
    float4 rv[4];

    auto sload = [&](int kt) {
#pragma unroll
        for (int it = 0; it < 4; ++it) {
            if (it == 3 && tid >= 128) continue;
            const float* xp = Xn + (size_t)(kt * 32 + s_cg[it] * 4) * HW + s_hw[it];
            rv[it].x = xp[0];
            rv[it].y = xp[HW];
            rv[it].z = xp[2 * HW];
            rv[it].w = xp[3 * HW];
        }
    };
    auto swrite = [&](int b) {
#pragma unroll
        for (int it = 0; it < 4; ++it) {
            if (it == 3 && tid >= 128) continue;
            ushort4 u;
            u.x = f2bf(rv[it].x); u.y = f2bf(rv[it].y);
            u.z = f2bf(rv[it].z); u.w = f2bf(rv[it].w);
            *reinterpret_cast<ushort4*>(&lds[b][s_hw[it] * 40 + s_cg[it] * 4]) = u;
        }
    };

    f32x4 acc[2][7];
#pragma unroll
    for (int i = 0; i < 2; ++i)
#pragma unroll
        for (int j = 0; j < 7; ++j) acc[i][j] = (f32x4)(0.f);

    const ushort* A0 = Wq + (size_t)(wv * 32 + colane) * 512 + klane;

    sload(0); swrite(0); __syncthreads();
    for (int kt = 0; kt < 16; ++kt) {
        if (kt < 15) sload(kt + 1);
        const int b = kt & 1;
        bf16x8 a0 = *reinterpret_cast<const bf16x8*>(A0 + kt * 32);
        bf16x8 a1 = *reinterpret_cast<const bf16x8*>(A0 + 16 * 512 + kt * 32);
#pragma unroll
        for (int j = 0; j < 7; ++j) {
            bf16x8 bb = *reinterpret_cast<const bf16x8*>(
                &lds[b][(j * 16 + colane) * 40 + klane]);
            acc[0][j] = __builtin_amdgcn_mfma_f32_16x16x32_bf16(a0, bb, acc[0][j], 0, 0, 0);
            acc[1][j] = __builtin_amdgcn_mfma_f32_16x16x32_bf16(a1, bb, acc[1][j], 0, 0, 0);
        }
        if (kt < 15) swrite(b ^ 1);
        __syncthreads();
    }
    epi_t(acc, y1t + (size_t)n * HW * 128 + (size_t)hwt * 112 * 128, part,
          128, n * 7 + hwt, wv * 32, colane, lanehi);
}

// ---------------------------------------------------------------------------
// conv2: 3x3 pad1. Reads RAW y1t, applies BN1+ReLU during halo staging.
// ---------------------------------------------------------------------------
__global__ __launch_bounds__(256, 2) void conv2_mfma(
    const ushort* __restrict__ y1t, const ushort* __restrict__ Wq,
    ushort* __restrict__ y2t, float* __restrict__ part,
    const float* __restrict__ rs1, const float* __restrict__ sh1)
{
    __shared__ ushort lds[2][2 * 6 * 30 * 40];
    const int n = blockIdx.z, hwt = blockIdx.x;
    const int tid = threadIdx.x, lane = tid & 63, wv = tid >> 6;
    const int colane = lane & 15, lanehi = lane >> 4, klane = lanehi * 8;
    const size_t noff = (size_t)n * HW * 128;
    const int h0 = hwt * 4;

    auto stage = [&](int p, int b) {
        for (int s = tid; s < 1440; s += 256) {
            int rr = s / 240, rem = s - rr * 240, ww = rem >> 3, sl = rem & 7;
            int cc = sl >> 2, g = sl & 3;
            int h = h0 - 1 + rr, w = ww - 1;
            int c0 = (2 * p + cc) * 32 + g * 8;
            uint4 v = make_uint4(0, 0, 0, 0);
            if ((unsigned)h < IW && (unsigned)w < IW) {
                v = *reinterpret_cast<const uint4*>(
                    &y1t[noff + (size_t)(h * IW + w) * 128 + c0]);
                v = bn_pack(v, rs1, sh1, c0);
            }
            *reinterpret_cast<uint4*>(&lds[b][((cc * 6 + rr) * 30 + ww) * 40 + g * 8]) = v;
        }
    };

    int base[7];
#pragma unroll
    for (int j = 0; j < 7; ++j) {
        int hwl = j * 16 + colane;
        int hl = hwl / 28, wl = hwl - hl * 28;
        base[j] = ((hl + 1) * 30 + (wl + 1)) * 40 + klane;
    }

    f32x4 acc[2][7];
#pragma unroll
    for (int i = 0; i < 2; ++i)
#pragma unroll
        for (int j = 0; j < 7; ++j) acc[i][j] = (f32x4)(0.f);

    const ushort* A0 = Wq + (size_t)(wv * 32 + colane) * 1152 + klane;

    auto compute = [&](int p, int b) {
        for (int r = 0; r < 9; ++r) {
            const int dh = r / 3 - 1, dw = r - (r / 3) * 3 - 1;
            const int delta = (dh * 30 + dw) * 40;
#pragma unroll
            for (int cc = 0; cc < 2; ++cc) {
                bf16x8 a0 = *reinterpret_cast<const bf16x8*>(
                    A0 + r * 128 + (2 * p + cc) * 32);
                bf16x8 a1 = *reinterpret_cast<const bf16x8*>(
                    A0 + 16 * 1152 + r * 128 + (2 * p + cc) * 32);
                const ushort* L = &lds[b][cc * 7200];
#pragma unroll
                for (int j = 0; j < 7; ++j) {
                    bf16x8 bb = *reinterpret_cast<const bf16x8*>(&L[base[j] + delta]);
                    acc[0][j] = __builtin_amdgcn_mfma_f32_16x16x32_bf16(a0, bb, acc[0][j], 0, 0, 0);
                    acc[1][j] = __builtin_amdgcn_mfma_f32_16x16x32_bf16(a1, bb, acc[1][j], 0, 0, 0);
                }
            }
        }
    };

    stage(0, 0);
    __syncthreads();

    uint4 pv[6];
#pragma unroll
    for (int it = 0; it < 6; ++it) {
        int s = tid + it * 256;
        if (it == 5 && tid >= 160) continue;
        int rr = s / 240, rem = s - rr * 240, ww = rem >> 3, sl = rem & 7;
        int cc = sl >> 2, g = sl & 3;
        int h = h0 - 1 + rr, w = ww - 1;
        int c0 = (2 + cc) * 32 + g * 8;
        uint4 v = make_uint4(0, 0, 0, 0);
        if ((unsigned)h < IW && (unsigned)w < IW) {
            v = *reinterpret_cast<const uint4*>(
                &y1t[noff + (size_t)(h * IW + w) * 128 + c0]);
            v = bn_pack(v, rs1, sh1, c0);
        }
        pv[it] = v;
    }

    compute(0, 0);

#pragma unroll
    for (int it = 0; it < 6; ++it) {
        int s = tid + it * 256;
        if (it == 5 && tid >= 160) continue;
        int rr = s / 240, rem = s - rr * 240, ww = rem >> 3, sl = rem & 7;
        int cc = sl >> 2, g = sl & 3;
        *reinterpret_cast<uint4*>(
            &lds[1][((cc * 6 + rr) * 30 + ww) * 40 + g * 8]) = pv[it];
    }
    __syncthreads();
    compute(1, 1);

    epi_t(acc, y2t + noff + (size_t)hwt * 112 * 128, part,
          128, n * 7 + hwt, wv * 32, colane, lanehi);
}

// ---------------------------------------------------------------------------
// conv3_stats: 1x1 K=128. Stages BN2+ReLU(y2t) tile to LDS, computes conv3
// for all 4 co-tiles, writes ONLY BN3 partial stats (no y3 write).
// ---------------------------------------------------------------------------
__global__ __launch_bounds__(256, 2) void conv3_stats(
    const ushort* __restrict__ y2t, const ushort* __restrict__ Wq,
    float* __restrict__ part,
    const float* __restrict__ rs2, const float* __restrict__ sh2)
{
    __shared__ ushort B_lds[112 * 136];
    const int n = blockIdx.z, hwt = blockIdx.x;
    const int tid = threadIdx.x, lane = tid & 63, wv = tid >> 6;
    const int colane = lane & 15, lanehi = lane >> 4, klane = lanehi * 8;
    const size_t noff = (size_t)n * HW * 128;

    for (int s = tid; s < 1792; s += 256) {
        int hw = s >> 4, g = s & 15, c0 = g * 8;
        uint4 v = *reinterpret_cast<const uint4*>(
            &y2t[noff + (size_t)(hwt * 112 + hw) * 128 + c0]);
        v = bn_pack(v, rs2, sh2, c0);
        *reinterpret_cast<uint4*>(&B_lds[hw * 136 + c0]) = v;
    }
    __syncthreads();

#pragma unroll 1
    for (int cot = 0; cot < 4; ++cot) {
        const int co0 = cot * 128 + wv * 32;
        f32x4 acc[2][7];
#pragma unroll
        for (int i = 0; i < 2; ++i)
#pragma unroll
            for (int j = 0; j < 7; ++j) acc[i][j] = (f32x4)(0.f);

        const ushort* A0 = Wq + (size_t)(co0 + colane) * 128 + klane;
#pragma unroll
        for (int kt = 0; kt < 4; ++kt) {
            bf16x8 a0 = *reinterpret_cast<const bf16x8*>(A0 + kt * 32);
            bf16x8 a1 = *reinterpret_cast<const bf16x8*>(A0 + 16 * 128 + kt * 32);
#pragma unroll
            for (int j = 0; j < 7; ++j) {
                bf16x8 bb = *reinterpret_cast<const bf16x8*>(
                    &B_lds[(j * 16 + colane) * 136 + kt * 32 + klane]);
                acc[0][j] = __builtin_amdgcn_mfma_f32_16x16x32_bf16(a0, bb, acc[0][j], 0, 0, 0);
                acc[1][j] = __builtin_amdgcn_mfma_f32_16x16x32_bf16(a1, bb, acc[1][j], 0, 0, 0);
            }
        }

#pragma unroll
        for (int fi = 0; fi < 2; ++fi) {
            float s[4] = {0, 0, 0, 0}, q[4] = {0, 0, 0, 0};
#pragma unroll
            for (int j = 0; j < 7; ++j)
#pragma unroll
                for (int r = 0; r < 4; ++r) {
                    float v = acc[fi][j][r];
                    s[r] += v; q[r] += v * v;
                }
#pragma unroll
            for (int m = 1; m < 16; m <<= 1)
#pragma unroll
                for (int r = 0; r < 4; ++r) {
                    s[r] += __shfl_xor(s[r], m, 64);
                    q[r] += __shfl_xor(q[r], m, 64);
                }
            if (colane == 0) {
#pragma unroll
                for (int r = 0; r < 4; ++r) {
                    int co = co0 + fi * 16 + lanehi * 4 + r;
                    part[(size_t)co * 448 + (n * 7 + hwt)]         = s[r];
                    part[(size_t)(512 + co) * 448 + (n * 7 + hwt)] = q[r];
                }
            }
        }
    }
}

// ---------------------------------------------------------------------------
// conv3_final: recompute conv3 from y2t (L2-resident), then fused
// BN3 + residual + ReLU -> out, staged through LDS for coalescing.
// ---------------------------------------------------------------------------
__global__ __launch_bounds__(256, 2) void conv3_final(
    const ushort* __restrict__ y2t, const ushort* __restrict__ Wq,
    const float* __restrict__ X, float* __restrict__ out,
    const float* __restrict__ rs2, const float* __restrict__ sh2,
    const float* __restrict__ rs3, const float* __restrict__ sh3)
{
    __shared__ ushort B_lds[112 * 136];
    __shared__ ushort O_lds[128 * 120];
    __shared__ float  C_lds[1024];
    const int n = blockIdx.z, hwt = blockIdx.x;
    const int tid = threadIdx.x, lane = tid & 63, wv = tid >> 6;
    const int colane = lane & 15, lanehi = lane >> 4, klane = lanehi * 8;
    const size_t noff = (size_t)n * HW * 128;

    for (int s = tid; s < 1792; s += 256) {
        int hw = s >> 4, g = s & 15, c0 = g * 8;
        uint4 v = *reinterpret_cast<const uint4*>(
            &y2t[noff + (size_t)(hwt * 112 + hw) * 128 + c0]);
        v = bn_pack(v, rs2, sh2, c0);
        *reinterpret_cast<uint4*>(&B_lds[hw * 136 + c0]) = v;
    }
    for (int i = tid; i < 1024; i += 256)
        C_lds[i] = (i < 512) ? rs3[i] : sh3[i - 512];
    __syncthreads();

#pragma unroll 1
    for (int cot = 0; cot < 4; ++cot) {
        const int co0 = cot * 128 + wv * 32;
        f32x4 acc[2][7];
#pragma unroll
        for (int i = 0; i < 2; ++i)
#pragma unroll
            for (int j = 0; j < 7; ++j) acc[i][j] = (f32x4)(0.f);

        const ushort* A0 = Wq + (size_t)(co0 + colane) * 128 + klane;
#pragma unroll
        for (int kt = 0; kt < 4; ++kt) {
            bf16x8 a0 = *reinterpret_cast<const bf16x8*>(A0 + kt * 32);
            bf16x8 a1 = *reinterpret_cast<const bf16x8*>(A0 + 16 * 128 + kt * 32);
#pragma unroll
            for (int j = 0; j < 7; ++j) {
                bf16x8 bb = *reinterpret_cast<const bf16x8*>(
                    &B_lds[(j * 16 + colane) * 136 + kt * 32 + klane]);
                acc[0][j] = __builtin_amdgcn_mfma_f32_16x16x32_bf16(a0, bb, acc[0][j], 0, 0, 0);
                acc[1][j] = __builtin_amdgcn_mfma_f32_16x16x32_bf16(a1, bb, acc[1][j], 0, 0, 0);
            }
        }

#pragma unroll
        for (int fi = 0; fi < 2; ++fi)
#pragma unroll
            for (int j = 0; j < 7; ++j) {
                int rowb = (wv * 32 + fi * 16 + lanehi * 4) * 120 + j * 16 + colane;
#pragma unroll
                for (int r = 0; r < 4; ++r)
                    O_lds[rowb + r * 120] = f2bf(acc[fi][j][r]);
            }
        __syncthreads();

        const float* xb = X + ((size_t)n * 512 + cot * 128) * HW + hwt * 112;
        float* ob = out + ((size_t)n * 512 + cot * 128) * HW + hwt * 112;
#pragma unroll
        for (int it = 0; it < 14; ++it) {
            int slot = it * 256 + tid;
            int row = slot / 28, c4 = slot - row * 28;
            float r3 = C_lds[cot * 128 + row];
            float s3 = C_lds[512 + cot * 128 + row];
            ushort4 yv = *reinterpret_cast<const ushort4*>(
                &O_lds[row * 120 + c4 * 4]);
            float4 xv = *reinterpret_cast<const float4*>(
                xb + (size_t)row * HW + c4 * 4);
            float4 o;
            o.x = fmaxf(fmaf(bf2f(yv.x), r3, s3) + xv.x, 0.f);
            o.y = fmaxf(fmaf(bf2f(yv.y), r3, s3) + xv.y, 0.f);
            o.z = fmaxf(fmaf(bf2f(yv.z), r3, s3) + xv.z, 0.f);
            o.w = fmaxf(fmaf(bf2f(yv.w), r3, s3) + xv.w, 0.f);
            *reinterpret_cast<float4*>(ob + (size_t)row * HW + c4 * 4) = o;
        }
        __syncthreads();
    }
}

// ---------------------------------------------------------------------------
// finalize: partials[2C][448] -> rs[c], sh[c]
// ---------------------------------------------------------------------------
__global__ void finalize_stats(const float* __restrict__ part, int C,
    const float* __restrict__ gamma, const float* __restrict__ beta,
    float* __restrict__ rs, float* __restrict__ sh)
{
    int c = blockIdx.x, lane = threadIdx.x;
    double s = 0.0, s2 = 0.0;
    for (int i = lane; i < 448; i += 64) {
        s  += part[(size_t)c * 448 + i];
        s2 += part[(size_t)(C + c) * 448 + i];
    }
#pragma unroll
    for (int m = 1; m < 64; m <<= 1) {
        s  += __shfl_xor(s, m, 64);
        s2 += __shfl_xor(s2, m, 64);
    }
    if (lane == 0) {
        double tot = (double)NB * HW;
        double mean = s / tot;
        float var = (float)(s2 / tot - mean * mean);
        float r = rsqrtf(var + BN_EPS) * gamma[c];
        rs[c] = r;
        sh[c] = beta[c] - (float)mean * r;
    }
}

// ---------------------------------------------------------------------------
extern "C" void kernel_launch(void* const* d_in, const int* in_sizes, int n_in,
                              void* d_out, int out_size, void* d_ws, size_t ws_size,
                              hipStream_t stream)
{
    const float* x   = (const float*)d_in[0];
    const float* w1  = (const float*)d_in[1];
    const float* g1  = (const float*)d_in[3];
    const float* be1 = (const float*)d_in[4];
    const float* w2  = (const float*)d_in[5];
    const float* g2  = (const float*)d_in[7];
    const float* be2 = (const float*)d_in[8];
    const float* w3  = (const float*)d_in[9];
    const float* g3  = (const float*)d_in[11];
    const float* be3 = (const float*)d_in[12];
    float* out = (float*)d_out;

    char* wsb = (char*)d_ws;
    float* rs1 = (float*)(wsb + 1024);
    float* sh1 = (float*)(wsb + 1536);
    float* rs2 = (float*)(wsb + 2048);
    float* sh2 = (float*)(wsb + 2560);
    float* rs3 = (float*)(wsb + 3072);
    float* sh3 = (float*)(wsb + 5120);
    float* part1 = (float*)(wsb + 8192);      // [256][448]
    float* part2 = (float*)(wsb + 466944);    // [256][448]
    float* part3 = (float*)(wsb + 925696);    // [1024][448]
    ushort* Wq1 = (ushort*)(wsb + 2760704);
    ushort* Wq2 = (ushort*)(wsb + 2891776);
    ushort* Wq3 = (ushort*)(wsb + 3186688);
    ushort* y1t = (ushort*)(wsb + 3317760);
    ushort* y2t = (ushort*)(wsb + 16162816);

    prep_kernel<<<3, 1024, 0, stream>>>(w1, w2, w3, Wq1, Wq2, Wq3);

    conv1_mfma<<<dim3(7, 1, NB), 256, 0, stream>>>(x, Wq1, y1t, part1);
    finalize_stats<<<128, 64, 0, stream>>>(part1, 128, g1, be1, rs1, sh1);

    conv2_mfma<<<dim3(7, 1, NB), 256, 0, stream>>>(y1t, Wq2, y2t, part2,
                                                   rs1, sh1);
    finalize_stats<<<128, 64, 0, stream>>>(part2, 128, g2, be2, rs2, sh2);

    conv3_stats<<<dim3(7, 1, NB), 256, 0, stream>>>(y2t, Wq3, part3, rs2, sh2);
    finalize_stats<<<512, 64, 0, stream>>>(part3, 512, g3, be3, rs3, sh3);

    conv3_final<<<dim3(7, 1, NB), 256, 0, stream>>>(y2t, Wq3, x, out,
                                                    rs2, sh2, rs3, sh3);
}

// Round 12
// 154.287 us; speedup vs baseline: 1.2889x; 1.2889x over previous
//
#include <hip/hip_runtime.h>
#include <hip/hip_bf16.h>
#include <math.h>

#define HW 784
#define IW 28
#define NB 64
#define BN_EPS 1e-5f

typedef __attribute__((ext_vector_type(8))) short bf16x8;
typedef __attribute__((ext_vector_type(4))) float f32x4;

static __device__ __forceinline__ ushort f2bf(float f) {
    __hip_bfloat16 h = __float2bfloat16(f);
    return *reinterpret_cast<ushort*>(&h);
}
static __device__ __forceinline__ float bf2f(ushort u) {
    return __uint_as_float(((unsigned)u) << 16);
}

// BN+ReLU on a packed 8-channel bf16 uint4, channels [c0..c0+8)
static __device__ __forceinline__ uint4 bn_pack(uint4 v,
    const float* __restrict__ rs, const float* __restrict__ sh, int c0)
{
    float4 ra = *reinterpret_cast<const float4*>(rs + c0);
    float4 rb = *reinterpret_cast<const float4*>(rs + c0 + 4);
    float4 sa = *reinterpret_cast<const float4*>(sh + c0);
    float4 sb = *reinterpret_cast<const float4*>(sh + c0 + 4);
    ushort* u = (ushort*)&v;
    u[0] = f2bf(fmaxf(fmaf(bf2f(u[0]), ra.x, sa.x), 0.f));
    u[1] = f2bf(fmaxf(fmaf(bf2f(u[1]), ra.y, sa.y), 0.f));
    u[2] = f2bf(fmaxf(fmaf(bf2f(u[2]), ra.z, sa.z), 0.f));
    u[3] = f2bf(fmaxf(fmaf(bf2f(u[3]), ra.w, sa.w), 0.f));
    u[4] = f2bf(fmaxf(fmaf(bf2f(u[4]), rb.x, sb.x), 0.f));
    u[5] = f2bf(fmaxf(fmaf(bf2f(u[5]), rb.y, sb.y), 0.f));
    u[6] = f2bf(fmaxf(fmaf(bf2f(u[6]), rb.z, sb.z), 0.f));
    u[7] = f2bf(fmaxf(fmaf(bf2f(u[7]), rb.w, sb.w), 0.f));
    return v;
}

// ---------------------------------------------------------------------------
// merged absmax for all 3 weight tensors (blockIdx.y = tensor id)
// ---------------------------------------------------------------------------
__global__ void absmax3_kernel(const float* __restrict__ w1,
                               const float* __restrict__ w2,
                               const float* __restrict__ w3,
                               unsigned int* __restrict__ slots) {
    const int t = blockIdx.y;
    const float* w = t == 0 ? w1 : (t == 1 ? w2 : w3);
    const int n = (t == 1) ? 147456 : 65536;
    float m = 0.f;
    for (int i = blockIdx.x * blockDim.x + threadIdx.x; i < n;
         i += gridDim.x * blockDim.x)
        m = fmaxf(m, fabsf(w[i]));
#pragma unroll
    for (int off = 32; off > 0; off >>= 1)
        m = fmaxf(m, __shfl_down(m, off, 64));
    __shared__ float sm[4];
    int lane = threadIdx.x & 63, wid = threadIdx.x >> 6;
    if (lane == 0) sm[wid] = m;
    __syncthreads();
    if (threadIdx.x == 0) {
        float b = fmaxf(fmaxf(sm[0], sm[1]), fmaxf(sm[2], sm[3]));
        atomicMax(slots + t, __float_as_uint(b));
    }
}

// ---------------------------------------------------------------------------
// merged prequant: w1,w3 same-layout; w2 -> [co][r*128+ci] transpose
// ---------------------------------------------------------------------------
__global__ void prequant3_kernel(const float* __restrict__ w1,
                                 const float* __restrict__ w2,
                                 const float* __restrict__ w3,
                                 const unsigned int* __restrict__ amax,
                                 ushort* __restrict__ o1,
                                 ushort* __restrict__ o2,
                                 ushort* __restrict__ o3) {
    const int t = blockIdx.y;
    const float* w = t == 0 ? w1 : (t == 1 ? w2 : w3);
    ushort* o = t == 0 ? o1 : (t == 1 ? o2 : o3);
    const int n = (t == 1) ? 147456 : 65536;
    float am = __uint_as_float(amax[t]);
    float scale = am * (1.0f / 127.0f);
    float inv   = 127.0f / am;
    for (int i = blockIdx.x * blockDim.x + threadIdx.x; i < n;
         i += gridDim.x * blockDim.x) {
        float q = rintf(w[i] * inv) * scale;
        if (t == 1) {
            int co  = i / 1152;
            int rem = i - co * 1152;
            int ci  = rem / 9;
            int r   = rem - ci * 9;
            o[co * 1152 + r * 128 + ci] = f2bf(q);
        } else {
            o[i] = f2bf(q);
        }
    }
}

// ---------------------------------------------------------------------------
// shared epilogue: write transposed bf16 [hw][C] + per-channel partial stats
// ---------------------------------------------------------------------------
__device__ __forceinline__ void epi_t(
    f32x4 (*acc)[7], ushort* __restrict__ yt_img, float* __restrict__ part,
    int C, int pb, int co0, int colane, int lanehi)
{
#pragma unroll
    for (int fi = 0; fi < 2; ++fi) {
#pragma unroll
        for (int j = 0; j < 7; ++j) {
            int hw = j * 16 + colane;
            int co = co0 + fi * 16 + lanehi * 4;
            ushort4 u;
            u.x = f2bf(acc[fi][j][0]); u.y = f2bf(acc[fi][j][1]);
            u.z = f2bf(acc[fi][j][2]); u.w = f2bf(acc[fi][j][3]);
            *reinterpret_cast<ushort4*>(&yt_img[(size_t)hw * C + co]) = u;
        }
        float s[4] = {0, 0, 0, 0}, q[4] = {0, 0, 0, 0};
#pragma unroll
        for (int j = 0; j < 7; ++j)
#pragma unroll
            for (int r = 0; r < 4; ++r) {
                float v = acc[fi][j][r];
                s[r] += v; q[r] += v * v;
            }
#pragma unroll
        for (int m = 1; m < 16; m <<= 1)
#pragma unroll
            for (int r = 0; r < 4; ++r) {
                s[r] += __shfl_xor(s[r], m, 64);
                q[r] += __shfl_xor(q[r], m, 64);
            }
        if (colane == 0) {
#pragma unroll
            for (int r = 0; r < 4; ++r) {
                int co = co0 + fi * 16 + lanehi * 4 + r;
                part[(size_t)co * 448 + pb]       = s[r];
                part[(size_t)(C + co) * 448 + pb] = q[r];
            }
        }
    }
}

// ---------------------------------------------------------------------------
// conv1: 1x1 K=512, fp32 x[n][ci][hw] -> RAW y1t[n][hw][128] bf16 + stats
// ---------------------------------------------------------------------------
__global__ __launch_bounds__(256, 2) void conv1_mfma(
    const float* __restrict__ X, const ushort* __restrict__ Wq,
    ushort* __restrict__ y1t, float* __restrict__ part)
{
    __shared__ ushort lds[2][112 * 40];
    const int n = blockIdx.z, hwt = blockIdx.x;
    const int tid = threadIdx.x, lane = tid & 63, wv = tid >> 6;
    const int colane = lane & 15, lanehi = lane >> 4, klane = lanehi * 8;
    const float* __restrict__ Xn = X + (size_t)n * 512 * HW + hwt * 112;

    int s_hw[4], s_cg[4];
#pragma unroll
    for (int it = 0; it < 4; ++it) {
        int idx = tid + it * 256;
        s_hw[it] = idx % 112; s_cg[it] = idx / 112;
    }
    float4 rv[4];

    auto sload = [&](int kt) {
#pragma unroll
        for (int it = 0; it < 4; ++it) {
            if (it == 3 && tid >= 128) continue;
            const float* xp = Xn + (size_t)(kt * 32 + s_cg[it] * 4) * HW + s_hw[it];
            rv[it].x = xp[0];
            rv[it].y = xp[HW];
            rv[it].z = xp[2 * HW];
            rv[it].w = xp[3 * HW];
        }
    };
    auto swrite = [&](int b) {
#pragma unroll
        for (int it = 0; it < 4; ++it) {
            if (it == 3 && tid >= 128) continue;
            ushort4 u;
            u.x = f2bf(rv[it].x); u.y = f2bf(rv[it].y);
            u.z = f2bf(rv[it].z); u.w = f2bf(rv[it].w);
            *reinterpret_cast<ushort4*>(&lds[b][s_hw[it] * 40 + s_cg[it] * 4]) = u;
        }
    };

    f32x4 acc[2][7];
#pragma unroll
    for (int i = 0; i < 2; ++i)
#pragma unroll
        for (int j = 0; j < 7; ++j) acc[i][j] = (f32x4)(0.f);

    const ushort* A0 = Wq + (size_t)(wv * 32 + colane) * 512 + klane;

    sload(0); swrite(0); __syncthreads();
    for (int kt = 0; kt < 16; ++kt) {
        if (kt < 15) sload(kt + 1);
        const int b = kt & 1;
        bf16x8 a0 = *reinterpret_cast<const bf16x8*>(A0 + kt * 32);
        bf16x8 a1 = *reinterpret_cast<const bf16x8*>(A0 + 16 * 512 + kt * 32);
#pragma unroll
        for (int j = 0; j < 7; ++j) {
            bf16x8 bb = *reinterpret_cast<const bf16x8*>(
                &lds[b][(j * 16 + colane) * 40 + klane]);
            acc[0][j] = __builtin_amdgcn_mfma_f32_16x16x32_bf16(a0, bb, acc[0][j], 0, 0, 0);
            acc[1][j] = __builtin_amdgcn_mfma_f32_16x16x32_bf16(a1, bb, acc[1][j], 0, 0, 0);
        }
        if (kt < 15) swrite(b ^ 1);
        __syncthreads();
    }
    epi_t(acc, y1t + (size_t)n * HW * 128 + (size_t)hwt * 112 * 128, part,
          128, n * 7 + hwt, wv * 32, colane, lanehi);
}

// ---------------------------------------------------------------------------
// conv2: 3x3 pad1. Reads RAW y1t, applies BN1+ReLU during halo staging.
// ---------------------------------------------------------------------------
__global__ __launch_bounds__(256, 2) void conv2_mfma(
    const ushort* __restrict__ y1t, const ushort* __restrict__ Wq,
    ushort* __restrict__ y2t, float* __restrict__ part,
    const float* __restrict__ rs1, const float* __restrict__ sh1)
{
    __shared__ ushort lds[2][2 * 6 * 30 * 40];
    const int n = blockIdx.z, hwt = blockIdx.x;
    const int tid = threadIdx.x, lane = tid & 63, wv = tid >> 6;
    const int colane = lane & 15, lanehi = lane >> 4, klane = lanehi * 8;
    const size_t noff = (size_t)n * HW * 128;
    const int h0 = hwt * 4;

    auto stage = [&](int p, int b) {
        for (int s = tid; s < 1440; s += 256) {
            int rr = s / 240, rem = s - rr * 240, ww = rem >> 3, sl = rem & 7;
            int cc = sl >> 2, g = sl & 3;
            int h = h0 - 1 + rr, w = ww - 1;
            int c0 = (2 * p + cc) * 32 + g * 8;
            uint4 v = make_uint4(0, 0, 0, 0);
            if ((unsigned)h < IW && (unsigned)w < IW) {
                v = *reinterpret_cast<const uint4*>(
                    &y1t[noff + (size_t)(h * IW + w) * 128 + c0]);
                v = bn_pack(v, rs1, sh1, c0);
            }
            *reinterpret_cast<uint4*>(&lds[b][((cc * 6 + rr) * 30 + ww) * 40 + g * 8]) = v;
        }
    };

    int base[7];
#pragma unroll
    for (int j = 0; j < 7; ++j) {
        int hwl = j * 16 + colane;
        int hl = hwl / 28, wl = hwl - hl * 28;
        base[j] = ((hl + 1) * 30 + (wl + 1)) * 40 + klane;
    }

    f32x4 acc[2][7];
#pragma unroll
    for (int i = 0; i < 2; ++i)
#pragma unroll
        for (int j = 0; j < 7; ++j) acc[i][j] = (f32x4)(0.f);

    const ushort* A0 = Wq + (size_t)(wv * 32 + colane) * 1152 + klane;

    auto compute = [&](int p, int b) {
        for (int r = 0; r < 9; ++r) {
            const int dh = r / 3 - 1, dw = r - (r / 3) * 3 - 1;
            const int delta = (dh * 30 + dw) * 40;
#pragma unroll
            for (int cc = 0; cc < 2; ++cc) {
                bf16x8 a0 = *reinterpret_cast<const bf16x8*>(
                    A0 + r * 128 + (2 * p + cc) * 32);
                bf16x8 a1 = *reinterpret_cast<const bf16x8*>(
                    A0 + 16 * 1152 + r * 128 + (2 * p + cc) * 32);
                const ushort* L = &lds[b][cc * 7200];
#pragma unroll
                for (int j = 0; j < 7; ++j) {
                    bf16x8 bb = *reinterpret_cast<const bf16x8*>(&L[base[j] + delta]);
                    acc[0][j] = __builtin_amdgcn_mfma_f32_16x16x32_bf16(a0, bb, acc[0][j], 0, 0, 0);
                    acc[1][j] = __builtin_amdgcn_mfma_f32_16x16x32_bf16(a1, bb, acc[1][j], 0, 0, 0);
                }
            }
        }
    };

    stage(0, 0);
    __syncthreads();

    uint4 pv[6];
#pragma unroll
    for (int it = 0; it < 6; ++it) {
        int s = tid + it * 256;
        if (it == 5 && tid >= 160) continue;
        int rr = s / 240, rem = s - rr * 240, ww = rem >> 3, sl = rem & 7;
        int cc = sl >> 2, g = sl & 3;
        int h = h0 - 1 + rr, w = ww - 1;
        int c0 = (2 + cc) * 32 + g * 8;
        uint4 v = make_uint4(0, 0, 0, 0);
        if ((unsigned)h < IW && (unsigned)w < IW) {
            v = *reinterpret_cast<const uint4*>(
                &y1t[noff + (size_t)(h * IW + w) * 128 + c0]);
            v = bn_pack(v, rs1, sh1, c0);
        }
        pv[it] = v;
    }

    compute(0, 0);

#pragma unroll
    for (int it = 0; it < 6; ++it) {
        int s = tid + it * 256;
        if (it == 5 && tid >= 160) continue;
        int rr = s / 240, rem = s - rr * 240, ww = rem >> 3, sl = rem & 7;
        int cc = sl >> 2, g = sl & 3;
        *reinterpret_cast<uint4*>(
            &lds[1][((cc * 6 + rr) * 30 + ww) * 40 + g * 8]) = pv[it];
    }
    __syncthreads();
    compute(1, 1);

    epi_t(acc, y2t + noff + (size_t)hwt * 112 * 128, part,
          128, n * 7 + hwt, wv * 32, colane, lanehi);
}

// ---------------------------------------------------------------------------
// conv3_stats: 1x1 K=128, cot = blockIdx.y (4-way parallel, no cot loop).
// Stages BN2+ReLU(y2t) tile to LDS, computes one 128-co tile, writes ONLY
// BN3 partial stats.
// ---------------------------------------------------------------------------
__global__ __launch_bounds__(256, 2) void conv3_stats(
    const ushort* __restrict__ y2t, const ushort* __restrict__ Wq,
    float* __restrict__ part,
    const float* __restrict__ rs2, const float* __restrict__ sh2)
{
    __shared__ ushort B_lds[112 * 136];
    const int n = blockIdx.z, hwt = blockIdx.x, cot = blockIdx.y;
    const int tid = threadIdx.x, lane = tid & 63, wv = tid >> 6;
    const int colane = lane & 15, lanehi = lane >> 4, klane = lanehi * 8;
    const size_t noff = (size_t)n * HW * 128;

    for (int s = tid; s < 1792; s += 256) {
        int hw = s >> 4, g = s & 15, c0 = g * 8;
        uint4 v = *reinterpret_cast<const uint4*>(
            &y2t[noff + (size_t)(hwt * 112 + hw) * 128 + c0]);
        v = bn_pack(v, rs2, sh2, c0);
        *reinterpret_cast<uint4*>(&B_lds[hw * 136 + c0]) = v;
    }
    __syncthreads();

    const int co0 = cot * 128 + wv * 32;
    f32x4 acc[2][7];
#pragma unroll
    for (int i = 0; i < 2; ++i)
#pragma unroll
        for (int j = 0; j < 7; ++j) acc[i][j] = (f32x4)(0.f);

    const ushort* A0 = Wq + (size_t)(co0 + colane) * 128 + klane;
#pragma unroll
    for (int kt = 0; kt < 4; ++kt) {
        bf16x8 a0 = *reinterpret_cast<const bf16x8*>(A0 + kt * 32);
        bf16x8 a1 = *reinterpret_cast<const bf16x8*>(A0 + 16 * 128 + kt * 32);
#pragma unroll
        for (int j = 0; j < 7; ++j) {
            bf16x8 bb = *reinterpret_cast<const bf16x8*>(
                &B_lds[(j * 16 + colane) * 136 + kt * 32 + klane]);
            acc[0][j] = __builtin_amdgcn_mfma_f32_16x16x32_bf16(a0, bb, acc[0][j], 0, 0, 0);
            acc[1][j] = __builtin_amdgcn_mfma_f32_16x16x32_bf16(a1, bb, acc[1][j], 0, 0, 0);
        }
    }

#pragma unroll
    for (int fi = 0; fi < 2; ++fi) {
        float s[4] = {0, 0, 0, 0}, q[4] = {0, 0, 0, 0};
#pragma unroll
        for (int j = 0; j < 7; ++j)
#pragma unroll
            for (int r = 0; r < 4; ++r) {
                float v = acc[fi][j][r];
                s[r] += v; q[r] += v * v;
            }
#pragma unroll
        for (int m = 1; m < 16; m <<= 1)
#pragma unroll
            for (int r = 0; r < 4; ++r) {
                s[r] += __shfl_xor(s[r], m, 64);
                q[r] += __shfl_xor(q[r], m, 64);
            }
        if (colane == 0) {
#pragma unroll
            for (int r = 0; r < 4; ++r) {
                int co = co0 + fi * 16 + lanehi * 4 + r;
                part[(size_t)co * 448 + (n * 7 + hwt)]         = s[r];
                part[(size_t)(512 + co) * 448 + (n * 7 + hwt)] = q[r];
            }
        }
    }
}

// ---------------------------------------------------------------------------
// conv3_final: cot = blockIdx.y. Recompute conv3 from y2t (L2-resident),
// fused BN3 + residual + ReLU -> out, staged through LDS for coalescing.
// ---------------------------------------------------------------------------
__global__ __launch_bounds__(256, 2) void conv3_final(
    const ushort* __restrict__ y2t, const ushort* __restrict__ Wq,
    const float* __restrict__ X, float* __restrict__ out,
    const float* __restrict__ rs2, const float* __restrict__ sh2,
    const float* __restrict__ rs3, const float* __restrict__ sh3)
{
    __shared__ ushort B_lds[112 * 136];
    __shared__ ushort O_lds[128 * 120];
    __shared__ float  C_lds[256];
    const int n = blockIdx.z, hwt = blockIdx.x, cot = blockIdx.y;
    const int tid = threadIdx.x, lane = tid & 63, wv = tid >> 6;
    const int colane = lane & 15, lanehi = lane >> 4, klane = lanehi * 8;
    const size_t noff = (size_t)n * HW * 128;

    for (int s = tid; s < 1792; s += 256) {
        int hw = s >> 4, g = s & 15, c0 = g * 8;
        uint4 v = *reinterpret_cast<const uint4*>(
            &y2t[noff + (size_t)(hwt * 112 + hw) * 128 + c0]);
        v = bn_pack(v, rs2, sh2, c0);
        *reinterpret_cast<uint4*>(&B_lds[hw * 136 + c0]) = v;
    }
    if (tid < 256) {
        C_lds[tid] = (tid < 128) ? rs3[cot * 128 + tid]
                                 : sh3[cot * 128 + tid - 128];
    }
    __syncthreads();

    const int co0 = cot * 128 + wv * 32;
    f32x4 acc[2][7];
#pragma unroll
    for (int i = 0; i < 2; ++i)
#pragma unroll
        for (int j = 0; j < 7; ++j) acc[i][j] = (f32x4)(0.f);

    const ushort* A0 = Wq + (size_t)(co0 + colane) * 128 + klane;
#pragma unroll
    for (int kt = 0; kt < 4; ++kt) {
        bf16x8 a0 = *reinterpret_cast<const bf16x8*>(A0 + kt * 32);
        bf16x8 a1 = *reinterpret_cast<const bf16x8*>(A0 + 16 * 128 + kt * 32);
#pragma unroll
        for (int j = 0; j < 7; ++j) {
            bf16x8 bb = *reinterpret_cast<const bf16x8*>(
                &B_lds[(j * 16 + colane) * 136 + kt * 32 + klane]);
            acc[0][j] = __builtin_amdgcn_mfma_f32_16x16x32_bf16(a0, bb, acc[0][j], 0, 0, 0);
            acc[1][j] = __builtin_amdgcn_mfma_f32_16x16x32_bf16(a1, bb, acc[1][j], 0, 0, 0);
        }
    }

#pragma unroll
    for (int fi = 0; fi < 2; ++fi)
#pragma unroll
        for (int j = 0; j < 7; ++j) {
            int rowb = (wv * 32 + fi * 16 + lanehi * 4) * 120 + j * 16 + colane;
#pragma unroll
            for (int r = 0; r < 4; ++r)
                O_lds[rowb + r * 120] = f2bf(acc[fi][j][r]);
        }
    __syncthreads();

    const float* xb = X + ((size_t)n * 512 + cot * 128) * HW + hwt * 112;
    float* ob = out + ((size_t)n * 512 + cot * 128) * HW + hwt * 112;
#pragma unroll
    for (int it = 0; it < 14; ++it) {
        int slot = it * 256 + tid;
        int row = slot / 28, c4 = slot - row * 28;
        float r3 = C_lds[row];
        float s3 = C_lds[128 + row];
        ushort4 yv = *reinterpret_cast<const ushort4*>(
            &O_lds[row * 120 + c4 * 4]);
        float4 xv = *reinterpret_cast<const float4*>(
            xb + (size_t)row * HW + c4 * 4);
        float4 o;
        o.x = fmaxf(fmaf(bf2f(yv.x), r3, s3) + xv.x, 0.f);
        o.y = fmaxf(fmaf(bf2f(yv.y), r3, s3) + xv.y, 0.f);
        o.z = fmaxf(fmaf(bf2f(yv.z), r3, s3) + xv.z, 0.f);
        o.w = fmaxf(fmaf(bf2f(yv.w), r3, s3) + xv.w, 0.f);
        *reinterpret_cast<float4*>(ob + (size_t)row * HW + c4 * 4) = o;
    }
}

// ---------------------------------------------------------------------------
// finalize: partials[2C][448] -> rs[c], sh[c]
// ---------------------------------------------------------------------------
__global__ void finalize_stats(const float* __restrict__ part, int C,
    const float* __restrict__ gamma, const float* __restrict__ beta,
    float* __restrict__ rs, float* __restrict__ sh)
{
    int c = blockIdx.x, lane = threadIdx.x;
    double s = 0.0, s2 = 0.0;
    for (int i = lane; i < 448; i += 64) {
        s  += part[(size_t)c * 448 + i];
        s2 += part[(size_t)(C + c) * 448 + i];
    }
#pragma unroll
    for (int m = 1; m < 64; m <<= 1) {
        s  += __shfl_xor(s, m, 64);
        s2 += __shfl_xor(s2, m, 64);
    }
    if (lane == 0) {
        double tot = (double)NB * HW;
        double mean = s / tot;
        float var = (float)(s2 / tot - mean * mean);
        float r = rsqrtf(var + BN_EPS) * gamma[c];
        rs[c] = r;
        sh[c] = beta[c] - (float)mean * r;
    }
}

// ---------------------------------------------------------------------------
extern "C" void kernel_launch(void* const* d_in, const int* in_sizes, int n_in,
                              void* d_out, int out_size, void* d_ws, size_t ws_size,
                              hipStream_t stream)
{
    const float* x   = (const float*)d_in[0];
    const float* w1  = (const float*)d_in[1];
    const float* g1  = (const float*)d_in[3];
    const float* be1 = (const float*)d_in[4];
    const float* w2  = (const float*)d_in[5];
    const float* g2  = (const float*)d_in[7];
    const float* be2 = (const float*)d_in[8];
    const float* w3  = (const float*)d_in[9];
    const float* g3  = (const float*)d_in[11];
    const float* be3 = (const float*)d_in[12];
    float* out = (float*)d_out;

    char* wsb = (char*)d_ws;
    unsigned int* amax = (unsigned int*)wsb;
    float* rs1 = (float*)(wsb + 1024);
    float* sh1 = (float*)(wsb + 1536);
    float* rs2 = (float*)(wsb + 2048);
    float* sh2 = (float*)(wsb + 2560);
    float* rs3 = (float*)(wsb + 3072);
    float* sh3 = (float*)(wsb + 5120);
    float* part1 = (float*)(wsb + 8192);      // [256][448]
    float* part2 = (float*)(wsb + 466944);    // [256][448]
    float* part3 = (float*)(wsb + 925696);    // [1024][448]
    ushort* Wq1 = (ushort*)(wsb + 2760704);
    ushort* Wq2 = (ushort*)(wsb + 2891776);
    ushort* Wq3 = (ushort*)(wsb + 3186688);
    ushort* y1t = (ushort*)(wsb + 3317760);
    ushort* y2t = (ushort*)(wsb + 16162816);

    (void)hipMemsetAsync(amax, 0, 64, stream);
    absmax3_kernel<<<dim3(32, 3), 256, 0, stream>>>(w1, w2, w3, amax);
    prequant3_kernel<<<dim3(96, 3), 256, 0, stream>>>(w1, w2, w3, amax,
                                                      Wq1, Wq2, Wq3);

    conv1_mfma<<<dim3(7, 1, NB), 256, 0, stream>>>(x, Wq1, y1t, part1);
    finalize_stats<<<128, 64, 0, stream>>>(part1, 128, g1, be1, rs1, sh1);

    conv2_mfma<<<dim3(7, 1, NB), 256, 0, stream>>>(y1t, Wq2, y2t, part2,
                                                   rs1, sh1);
    finalize_stats<<<128, 64, 0, stream>>>(part2, 128, g2, be2, rs2, sh2);

    conv3_stats<<<dim3(7, 4, NB), 256, 0, stream>>>(y2t, Wq3, part3, rs2, sh2);
    finalize_stats<<<512, 64, 0, stream>>>(part3, 512, g3, be3, rs3, sh3);

    conv3_final<<<dim3(7, 4, NB), 256, 0, stream>>>(y2t, Wq3, x, out,
                                                    rs2, sh2, rs3, sh3);
}

// Round 13
// 138.550 us; speedup vs baseline: 1.4353x; 1.1136x over previous
//
#include <hip/hip_runtime.h>
#include <hip/hip_bf16.h>
#include <math.h>

#define HW 784
#define IW 28
#define NB 64
#define BN_EPS 1e-5f

typedef __attribute__((ext_vector_type(8))) short bf16x8;
typedef __attribute__((ext_vector_type(4))) float f32x4;

static __device__ __forceinline__ ushort f2bf(float f) {
    __hip_bfloat16 h = __float2bfloat16(f);
    return *reinterpret_cast<ushort*>(&h);
}
static __device__ __forceinline__ float bf2f(ushort u) {
    return __uint_as_float(((unsigned)u) << 16);
}

// BN+ReLU on a packed 8-channel bf16 uint4, channels [c0..c0+8)
static __device__ __forceinline__ uint4 bn_pack(uint4 v,
    const float* __restrict__ rs, const float* __restrict__ sh, int c0)
{
    float4 ra = *reinterpret_cast<const float4*>(rs + c0);
    float4 rb = *reinterpret_cast<const float4*>(rs + c0 + 4);
    float4 sa = *reinterpret_cast<const float4*>(sh + c0);
    float4 sb = *reinterpret_cast<const float4*>(sh + c0 + 4);
    ushort* u = (ushort*)&v;
    u[0] = f2bf(fmaxf(fmaf(bf2f(u[0]), ra.x, sa.x), 0.f));
    u[1] = f2bf(fmaxf(fmaf(bf2f(u[1]), ra.y, sa.y), 0.f));
    u[2] = f2bf(fmaxf(fmaf(bf2f(u[2]), ra.z, sa.z), 0.f));
    u[3] = f2bf(fmaxf(fmaf(bf2f(u[3]), ra.w, sa.w), 0.f));
    u[4] = f2bf(fmaxf(fmaf(bf2f(u[4]), rb.x, sb.x), 0.f));
    u[5] = f2bf(fmaxf(fmaf(bf2f(u[5]), rb.y, sb.y), 0.f));
    u[6] = f2bf(fmaxf(fmaf(bf2f(u[6]), rb.z, sb.z), 0.f));
    u[7] = f2bf(fmaxf(fmaf(bf2f(u[7]), rb.w, sb.w), 0.f));
    return v;
}

// ---------------------------------------------------------------------------
// absmax partials: block (bx,t) writes its partial max to pmax[t*32+bx]
// (plain store, every slot written -> no zero-init, no atomics)
// ---------------------------------------------------------------------------
__global__ void absmax3_kernel(const float* __restrict__ w1,
                               const float* __restrict__ w2,
                               const float* __restrict__ w3,
                               float* __restrict__ pmax) {
    const int t = blockIdx.y;
    const float* w = t == 0 ? w1 : (t == 1 ? w2 : w3);
    const int n = (t == 1) ? 147456 : 65536;
    float m = 0.f;
    for (int i = blockIdx.x * blockDim.x + threadIdx.x; i < n;
         i += gridDim.x * blockDim.x)
        m = fmaxf(m, fabsf(w[i]));
#pragma unroll
    for (int off = 32; off > 0; off >>= 1)
        m = fmaxf(m, __shfl_down(m, off, 64));
    __shared__ float sm[4];
    int lane = threadIdx.x & 63, wid = threadIdx.x >> 6;
    if (lane == 0) sm[wid] = m;
    __syncthreads();
    if (threadIdx.x == 0)
        pmax[t * 32 + blockIdx.x] =
            fmaxf(fmaxf(sm[0], sm[1]), fmaxf(sm[2], sm[3]));
}

// ---------------------------------------------------------------------------
// merged prequant: reduces the 32 pmax partials in-wave, then quantizes.
// w1,w3 same-layout; w2 -> [co][r*128+ci] transpose
// ---------------------------------------------------------------------------
__global__ void prequant3_kernel(const float* __restrict__ w1,
                                 const float* __restrict__ w2,
                                 const float* __restrict__ w3,
                                 const float* __restrict__ pmax,
                                 ushort* __restrict__ o1,
                                 ushort* __restrict__ o2,
                                 ushort* __restrict__ o3) {
    const int t = blockIdx.y;
    const float* w = t == 0 ? w1 : (t == 1 ? w2 : w3);
    ushort* o = t == 0 ? o1 : (t == 1 ? o2 : o3);
    const int n = (t == 1) ? 147456 : 65536;

    float am = pmax[t * 32 + (threadIdx.x & 31)];
#pragma unroll
    for (int m = 1; m < 32; m <<= 1)
        am = fmaxf(am, __shfl_xor(am, m, 64));

    float scale = am * (1.0f / 127.0f);
    float inv   = 127.0f / am;
    for (int i = blockIdx.x * blockDim.x + threadIdx.x; i < n;
         i += gridDim.x * blockDim.x) {
        float q = rintf(w[i] * inv) * scale;
        if (t == 1) {
            int co  = i / 1152;
            int rem = i - co * 1152;
            int ci  = rem / 9;
            int r   = rem - ci * 9;
            o[co * 1152 + r * 128 + ci] = f2bf(q);
        } else {
            o[i] = f2bf(q);
        }
    }
}

// ---------------------------------------------------------------------------
// shared epilogue: write transposed bf16 [hw][C] + per-channel partial stats
// ---------------------------------------------------------------------------
__device__ __forceinline__ void epi_t(
    f32x4 (*acc)[7], ushort* __restrict__ yt_img, float* __restrict__ part,
    int C, int pb, int co0, int colane, int lanehi)
{
#pragma unroll
    for (int fi = 0; fi < 2; ++fi) {
#pragma unroll
        for (int j = 0; j < 7; ++j) {
            int hw = j * 16 + colane;
            int co = co0 + fi * 16 + lanehi * 4;
            ushort4 u;
            u.x = f2bf(acc[fi][j][0]); u.y = f2bf(acc[fi][j][1]);
            u.z = f2bf(acc[fi][j][2]); u.w = f2bf(acc[fi][j][3]);
            *reinterpret_cast<ushort4*>(&yt_img[(size_t)hw * C + co]) = u;
        }
        float s[4] = {0, 0, 0, 0}, q[4] = {0, 0, 0, 0};
#pragma unroll
        for (int j = 0; j < 7; ++j)
#pragma unroll
            for (int r = 0; r < 4; ++r) {
                float v = acc[fi][j][r];
                s[r] += v; q[r] += v * v;
            }
#pragma unroll
        for (int m = 1; m < 16; m <<= 1)
#pragma unroll
            for (int r = 0; r < 4; ++r) {
                s[r] += __shfl_xor(s[r], m, 64);
                q[r] += __shfl_xor(q[r], m, 64);
            }
        if (colane == 0) {
#pragma unroll
            for (int r = 0; r < 4; ++r) {
                int co = co0 + fi * 16 + lanehi * 4 + r;
                part[(size_t)co * 448 + pb]       = s[r];
                part[(size_t)(C + co) * 448 + pb] = q[r];
            }
        }
    }
}

// ---------------------------------------------------------------------------
// conv1: 1x1 K=512, fp32 x[n][ci][hw] -> RAW y1t[n][hw][128] bf16 + stats
// ---------------------------------------------------------------------------
__global__ __launch_bounds__(256, 2) void conv1_mfma(
    const float* __restrict__ X, const ushort* __restrict__ Wq,
    ushort* __restrict__ y1t, float* __restrict__ part)
{
    __shared__ ushort lds[2][112 * 40];
    const int n = blockIdx.z, hwt = blockIdx.x;
    const int tid = threadIdx.x, lane = tid & 63, wv = tid >> 6;
    const int colane = lane & 15, lanehi = lane >> 4, klane = lanehi * 8;
    const float* __restrict__ Xn = X + (size_t)n * 512 * HW + hwt * 112;

    int s_hw[4], s_cg[4];
#pragma unroll
    for (int it = 0; it < 4; ++it) {
        int idx = tid + it * 256;
        s_hw[it] = idx % 112; s_cg[it] = idx / 112;
    }
    float4 rv[4];

    auto sload = [&](int kt) {
#pragma unroll
        for (int it = 0; it < 4; ++it) {
            if (it == 3 && tid >= 128) continue;
            const float* xp = Xn + (size_t)(kt * 32 + s_cg[it] * 4) * HW + s_hw[it];
            rv[it].x = xp[0];
            rv[it].y = xp[HW];
            rv[it].z = xp[2 * HW];
            rv[it].w = xp[3 * HW];
        }
    };
    auto swrite = [&](int b) {
#pragma unroll
        for (int it = 0; it < 4; ++it) {
            if (it == 3 && tid >= 128) continue;
            ushort4 u;
            u.x = f2bf(rv[it].x); u.y = f2bf(rv[it].y);
            u.z = f2bf(rv[it].z); u.w = f2bf(rv[it].w);
            *reinterpret_cast<ushort4*>(&lds[b][s_hw[it] * 40 + s_cg[it] * 4]) = u;
        }
    };

    f32x4 acc[2][7];
#pragma unroll
    for (int i = 0; i < 2; ++i)
#pragma unroll
        for (int j = 0; j < 7; ++j) acc[i][j] = (f32x4)(0.f);

    const ushort* A0 = Wq + (size_t)(wv * 32 + colane) * 512 + klane;

    sload(0); swrite(0); __syncthreads();
    for (int kt = 0; kt < 16; ++kt) {
        if (kt < 15) sload(kt + 1);
        const int b = kt & 1;
        bf16x8 a0 = *reinterpret_cast<const bf16x8*>(A0 + kt * 32);
        bf16x8 a1 = *reinterpret_cast<const bf16x8*>(A0 + 16 * 512 + kt * 32);
#pragma unroll
        for (int j = 0; j < 7; ++j) {
            bf16x8 bb = *reinterpret_cast<const bf16x8*>(
                &lds[b][(j * 16 + colane) * 40 + klane]);
            acc[0][j] = __builtin_amdgcn_mfma_f32_16x16x32_bf16(a0, bb, acc[0][j], 0, 0, 0);
            acc[1][j] = __builtin_amdgcn_mfma_f32_16x16x32_bf16(a1, bb, acc[1][j], 0, 0, 0);
        }
        if (kt < 15) swrite(b ^ 1);
        __syncthreads();
    }
    epi_t(acc, y1t + (size_t)n * HW * 128 + (size_t)hwt * 112 * 128, part,
          128, n * 7 + hwt, wv * 32, colane, lanehi);
}

// ---------------------------------------------------------------------------
// conv2: 3x3 pad1. Reads RAW y1t, applies BN1+ReLU during halo staging.
// ---------------------------------------------------------------------------
__global__ __launch_bounds__(256, 2) void conv2_mfma(
    const ushort* __restrict__ y1t, const ushort* __restrict__ Wq,
    ushort* __restrict__ y2t, float* __restrict__ part,
    const float* __restrict__ rs1, const float* __restrict__ sh1)
{
    __shared__ ushort lds[2][2 * 6 * 30 * 40];
    const int n = blockIdx.z, hwt = blockIdx.x;
    const int tid = threadIdx.x, lane = tid & 63, wv = tid >> 6;
    const int colane = lane & 15, lanehi = lane >> 4, klane = lanehi * 8;
    const size_t noff = (size_t)n * HW * 128;
    const int h0 = hwt * 4;

    auto stage = [&](int p, int b) {
        for (int s = tid; s < 1440; s += 256) {
            int rr = s / 240, rem = s - rr * 240, ww = rem >> 3, sl = rem & 7;
            int cc = sl >> 2, g = sl & 3;
            int h = h0 - 1 + rr, w = ww - 1;
            int c0 = (2 * p + cc) * 32 + g * 8;
            uint4 v = make_uint4(0, 0, 0, 0);
            if ((unsigned)h < IW && (unsigned)w < IW) {
                v = *reinterpret_cast<const uint4*>(
                    &y1t[noff + (size_t)(h * IW + w) * 128 + c0]);
                v = bn_pack(v, rs1, sh1, c0);
            }
            *reinterpret_cast<uint4*>(&lds[b][((cc * 6 + rr) * 30 + ww) * 40 + g * 8]) = v;
        }
    };

    int base[7];
#pragma unroll
    for (int j = 0; j < 7; ++j) {
        int hwl = j * 16 + colane;
        int hl = hwl / 28, wl = hwl - hl * 28;
        base[j] = ((hl + 1) * 30 + (wl + 1)) * 40 + klane;
    }

    f32x4 acc[2][7];
#pragma unroll
    for (int i = 0; i < 2; ++i)
#pragma unroll
        for (int j = 0; j < 7; ++j) acc[i][j] = (f32x4)(0.f);

    const ushort* A0 = Wq + (size_t)(wv * 32 + colane) * 1152 + klane;

    auto compute = [&](int p, int b) {
        for (int r = 0; r < 9; ++r) {
            const int dh = r / 3 - 1, dw = r - (r / 3) * 3 - 1;
            const int delta = (dh * 30 + dw) * 40;
#pragma unroll
            for (int cc = 0; cc < 2; ++cc) {
                bf16x8 a0 = *reinterpret_cast<const bf16x8*>(
                    A0 + r * 128 + (2 * p + cc) * 32);
                bf16x8 a1 = *reinterpret_cast<const bf16x8*>(
                    A0 + 16 * 1152 + r * 128 + (2 * p + cc) * 32);
                const ushort* L = &lds[b][cc * 7200];
#pragma unroll
                for (int j = 0; j < 7; ++j) {
                    bf16x8 bb = *reinterpret_cast<const bf16x8*>(&L[base[j] + delta]);
                    acc[0][j] = __builtin_amdgcn_mfma_f32_16x16x32_bf16(a0, bb, acc[0][j], 0, 0, 0);
                    acc[1][j] = __builtin_amdgcn_mfma_f32_16x16x32_bf16(a1, bb, acc[1][j], 0, 0, 0);
                }
            }
        }
    };

    stage(0, 0);
    __syncthreads();

    uint4 pv[6];
#pragma unroll
    for (int it = 0; it < 6; ++it) {
        int s = tid + it * 256;
        if (it == 5 && tid >= 160) continue;
        int rr = s / 240, rem = s - rr * 240, ww = rem >> 3, sl = rem & 7;
        int cc = sl >> 2, g = sl & 3;
        int h = h0 - 1 + rr, w = ww - 1;
        int c0 = (2 + cc) * 32 + g * 8;
        uint4 v = make_uint4(0, 0, 0, 0);
        if ((unsigned)h < IW && (unsigned)w < IW) {
            v = *reinterpret_cast<const uint4*>(
                &y1t[noff + (size_t)(h * IW + w) * 128 + c0]);
            v = bn_pack(v, rs1, sh1, c0);
        }
        pv[it] = v;
    }

    compute(0, 0);

#pragma unroll
    for (int it = 0; it < 6; ++it) {
        int s = tid + it * 256;
        if (it == 5 && tid >= 160) continue;
        int rr = s / 240, rem = s - rr * 240, ww = rem >> 3, sl = rem & 7;
        int cc = sl >> 2, g = sl & 3;
        *reinterpret_cast<uint4*>(
            &lds[1][((cc * 6 + rr) * 30 + ww) * 40 + g * 8]) = pv[it];
    }
    __syncthreads();
    compute(1, 1);

    epi_t(acc, y2t + noff + (size_t)hwt * 112 * 128, part,
          128, n * 7 + hwt, wv * 32, colane, lanehi);
}

// ---------------------------------------------------------------------------
// conv3_stats: 1x1 K=128. Stages BN2+ReLU(y2t) tile to LDS ONCE, loops all
// 4 co-tiles (staging amortized), writes ONLY BN3 partial stats.
// ---------------------------------------------------------------------------
__global__ __launch_bounds__(256, 2) void conv3_stats(
    const ushort* __restrict__ y2t, const ushort* __restrict__ Wq,
    float* __restrict__ part,
    const float* __restrict__ rs2, const float* __restrict__ sh2)
{
    __shared__ ushort B_lds[112 * 136];
    const int n = blockIdx.z, hwt = blockIdx.x;
    const int tid = threadIdx.x, lane = tid & 63, wv = tid >> 6;
    const int colane = lane & 15, lanehi = lane >> 4, klane = lanehi * 8;
    const size_t noff = (size_t)n * HW * 128;

    for (int s = tid; s < 1792; s += 256) {
        int hw = s >> 4, g = s & 15, c0 = g * 8;
        uint4 v = *reinterpret_cast<const uint4*>(
            &y2t[noff + (size_t)(hwt * 112 + hw) * 128 + c0]);
        v = bn_pack(v, rs2, sh2, c0);
        *reinterpret_cast<uint4*>(&B_lds[hw * 136 + c0]) = v;
    }
    __syncthreads();

#pragma unroll 1
    for (int cot = 0; cot < 4; ++cot) {
        const int co0 = cot * 128 + wv * 32;
        f32x4 acc[2][7];
#pragma unroll
        for (int i = 0; i < 2; ++i)
#pragma unroll
            for (int j = 0; j < 7; ++j) acc[i][j] = (f32x4)(0.f);

        const ushort* A0 = Wq + (size_t)(co0 + colane) * 128 + klane;
#pragma unroll
        for (int kt = 0; kt < 4; ++kt) {
            bf16x8 a0 = *reinterpret_cast<const bf16x8*>(A0 + kt * 32);
            bf16x8 a1 = *reinterpret_cast<const bf16x8*>(A0 + 16 * 128 + kt * 32);
#pragma unroll
            for (int j = 0; j < 7; ++j) {
                bf16x8 bb = *reinterpret_cast<const bf16x8*>(
                    &B_lds[(j * 16 + colane) * 136 + kt * 32 + klane]);
                acc[0][j] = __builtin_amdgcn_mfma_f32_16x16x32_bf16(a0, bb, acc[0][j], 0, 0, 0);
                acc[1][j] = __builtin_amdgcn_mfma_f32_16x16x32_bf16(a1, bb, acc[1][j], 0, 0, 0);
            }
        }

#pragma unroll
        for (int fi = 0; fi < 2; ++fi) {
            float s[4] = {0, 0, 0, 0}, q[4] = {0, 0, 0, 0};
#pragma unroll
            for (int j = 0; j < 7; ++j)
#pragma unroll
                for (int r = 0; r < 4; ++r) {
                    float v = acc[fi][j][r];
                    s[r] += v; q[r] += v * v;
                }
#pragma unroll
            for (int m = 1; m < 16; m <<= 1)
#pragma unroll
                for (int r = 0; r < 4; ++r) {
                    s[r] += __shfl_xor(s[r], m, 64);
                    q[r] += __shfl_xor(q[r], m, 64);
                }
            if (colane == 0) {
#pragma unroll
                for (int r = 0; r < 4; ++r) {
                    int co = co0 + fi * 16 + lanehi * 4 + r;
                    part[(size_t)co * 448 + (n * 7 + hwt)]         = s[r];
                    part[(size_t)(512 + co) * 448 + (n * 7 + hwt)] = q[r];
                }
            }
        }
    }
}

// ---------------------------------------------------------------------------
// conv3_final: recompute conv3 from y2t (L2-resident), staging ONCE and
// looping co-tiles; fused BN3 + residual + ReLU -> out via LDS for
// coalesced x/out access.
// ---------------------------------------------------------------------------
__global__ __launch_bounds__(256, 2) void conv3_final(
    const ushort* __restrict__ y2t, const ushort* __restrict__ Wq,
    const float* __restrict__ X, float* __restrict__ out,
    const float* __restrict__ rs2, const float* __restrict__ sh2,
    const float* __restrict__ rs3, const float* __restrict__ sh3)
{
    __shared__ ushort B_lds[112 * 136];
    __shared__ ushort O_lds[128 * 120];
    __shared__ float  C_lds[1024];
    const int n = blockIdx.z, hwt = blockIdx.x;
    const int tid = threadIdx.x, lane = tid & 63, wv = tid >> 6;
    const int colane = lane & 15, lanehi = lane >> 4, klane = lanehi * 8;
    const size_t noff = (size_t)n * HW * 128;

    for (int s = tid; s < 1792; s += 256) {
        int hw = s >> 4, g = s & 15, c0 = g * 8;
        uint4 v = *reinterpret_cast<const uint4*>(
            &y2t[noff + (size_t)(hwt * 112 + hw) * 128 + c0]);
        v = bn_pack(v, rs2, sh2, c0);
        *reinterpret_cast<uint4*>(&B_lds[hw * 136 + c0]) = v;
    }
    for (int i = tid; i < 1024; i += 256)
        C_lds[i] = (i < 512) ? rs3[i] : sh3[i - 512];
    __syncthreads();

#pragma unroll 1
    for (int cot = 0; cot < 4; ++cot) {
        const int co0 = cot * 128 + wv * 32;
        f32x4 acc[2][7];
#pragma unroll
        for (int i = 0; i < 2; ++i)
#pragma unroll
            for (int j = 0; j < 7; ++j) acc[i][j] = (f32x4)(0.f);

        const ushort* A0 = Wq + (size_t)(co0 + colane) * 128 + klane;
#pragma unroll
        for (int kt = 0; kt < 4; ++kt) {
            bf16x8 a0 = *reinterpret_cast<const bf16x8*>(A0 + kt * 32);
            bf16x8 a1 = *reinterpret_cast<const bf16x8*>(A0 + 16 * 128 + kt * 32);
#pragma unroll
            for (int j = 0; j < 7; ++j) {
                bf16x8 bb = *reinterpret_cast<const bf16x8*>(
                    &B_lds[(j * 16 + colane) * 136 + kt * 32 + klane]);
                acc[0][j] = __builtin_amdgcn_mfma_f32_16x16x32_bf16(a0, bb, acc[0][j], 0, 0, 0);
                acc[1][j] = __builtin_amdgcn_mfma_f32_16x16x32_bf16(a1, bb, acc[1][j], 0, 0, 0);
            }
        }

#pragma unroll
        for (int fi = 0; fi < 2; ++fi)
#pragma unroll
            for (int j = 0; j < 7; ++j) {
                int rowb = (wv * 32 + fi * 16 + lanehi * 4) * 120 + j * 16 + colane;
#pragma unroll
                for (int r = 0; r < 4; ++r)
                    O_lds[rowb + r * 120] = f2bf(acc[fi][j][r]);
            }
        __syncthreads();

        const float* xb = X + ((size_t)n * 512 + cot * 128) * HW + hwt * 112;
        float* ob = out + ((size_t)n * 512 + cot * 128) * HW + hwt * 112;
#pragma unroll
        for (int it = 0; it < 14; ++it) {
            int slot = it * 256 + tid;
            int row = slot / 28, c4 = slot - row * 28;
            float r3 = C_lds[cot * 128 + row];
            float s3 = C_lds[512 + cot * 128 + row];
            ushort4 yv = *reinterpret_cast<const ushort4*>(
                &O_lds[row * 120 + c4 * 4]);
            float4 xv = *reinterpret_cast<const float4*>(
                xb + (size_t)row * HW + c4 * 4);
            float4 o;
            o.x = fmaxf(fmaf(bf2f(yv.x), r3, s3) + xv.x, 0.f);
            o.y = fmaxf(fmaf(bf2f(yv.y), r3, s3) + xv.y, 0.f);
            o.z = fmaxf(fmaf(bf2f(yv.z), r3, s3) + xv.z, 0.f);
            o.w = fmaxf(fmaf(bf2f(yv.w), r3, s3) + xv.w, 0.f);
            *reinterpret_cast<float4*>(ob + (size_t)row * HW + c4 * 4) = o;
        }
        __syncthreads();
    }
}

// ---------------------------------------------------------------------------
// finalize: partials[2C][448] -> rs[c], sh[c]
// ---------------------------------------------------------------------------
__global__ void finalize_stats(const float* __restrict__ part, int C,
    const float* __restrict__ gamma, const float* __restrict__ beta,
    float* __restrict__ rs, float* __restrict__ sh)
{
    int c = blockIdx.x, lane = threadIdx.x;
    double s = 0.0, s2 = 0.0;
    for (int i = lane; i < 448; i += 64) {
        s  += part[(size_t)c * 448 + i];
        s2 += part[(size_t)(C + c) * 448 + i];
    }
#pragma unroll
    for (int m = 1; m < 64; m <<= 1) {
        s  += __shfl_xor(s, m, 64);
        s2 += __shfl_xor(s2, m, 64);
    }
    if (lane == 0) {
        double tot = (double)NB * HW;
        double mean = s / tot;
        float var = (float)(s2 / tot - mean * mean);
        float r = rsqrtf(var + BN_EPS) * gamma[c];
        rs[c] = r;
        sh[c] = beta[c] - (float)mean * r;
    }
}

// ---------------------------------------------------------------------------
extern "C" void kernel_launch(void* const* d_in, const int* in_sizes, int n_in,
                              void* d_out, int out_size, void* d_ws, size_t ws_size,
                              hipStream_t stream)
{
    const float* x   = (const float*)d_in[0];
    const float* w1  = (const float*)d_in[1];
    const float* g1  = (const float*)d_in[3];
    const float* be1 = (const float*)d_in[4];
    const float* w2  = (const float*)d_in[5];
    const float* g2  = (const float*)d_in[7];
    const float* be2 = (const float*)d_in[8];
    const float* w3  = (const float*)d_in[9];
    const float* g3  = (const float*)d_in[11];
    const float* be3 = (const float*)d_in[12];
    float* out = (float*)d_out;

    char* wsb = (char*)d_ws;
    float* pmax = (float*)wsb;                // 96 slots, all written
    float* rs1 = (float*)(wsb + 1024);
    float* sh1 = (float*)(wsb + 1536);
    float* rs2 = (float*)(wsb + 2048);
    float* sh2 = (float*)(wsb + 2560);
    float* rs3 = (float*)(wsb + 3072);
    float* sh3 = (float*)(wsb + 5120);
    float* part1 = (float*)(wsb + 8192);      // [256][448]
    float* part2 = (float*)(wsb + 466944);    // [256][448]
    float* part3 = (float*)(wsb + 925696);    // [1024][448]
    ushort* Wq1 = (ushort*)(wsb + 2760704);
    ushort* Wq2 = (ushort*)(wsb + 2891776);
    ushort* Wq3 = (ushort*)(wsb + 3186688);
    ushort* y1t = (ushort*)(wsb + 3317760);
    ushort* y2t = (ushort*)(wsb + 16162816);

    absmax3_kernel<<<dim3(32, 3), 256, 0, stream>>>(w1, w2, w3, pmax);
    prequant3_kernel<<<dim3(96, 3), 256, 0, stream>>>(w1, w2, w3, pmax,
                                                      Wq1, Wq2, Wq3);

    conv1_mfma<<<dim3(7, 1, NB), 256, 0, stream>>>(x, Wq1, y1t, part1);
    finalize_stats<<<128, 64, 0, stream>>>(part1, 128, g1, be1, rs1, sh1);

    conv2_mfma<<<dim3(7, 1, NB), 256, 0, stream>>>(y1t, Wq2, y2t, part2,
                                                   rs1, sh1);
    finalize_stats<<<128, 64, 0, stream>>>(part2, 128, g2, be2, rs2, sh2);

    conv3_stats<<<dim3(7, 1, NB), 256, 0, stream>>>(y2t, Wq3, part3, rs2, sh2);
    finalize_stats<<<512, 64, 0, stream>>>(part3, 512, g3, be3, rs3, sh3);

    conv3_final<<<dim3(7, 1, NB), 256, 0, stream>>>(y2t, Wq3, x, out,
                                                    rs2, sh2, rs3, sh3);
}